// Round 1
// baseline (570.168 us; speedup 1.0000x reference)
//
#include <hip/hip_runtime.h>
#include <math.h>

#define BN 32
#define DN 128
#define NSTEP 31          // Bn - 1
#define NT 1024

__device__ __forceinline__ float sigf(float x) { return 1.0f / (1.0f + expf(-x)); }

// One persistent workgroup runs the whole 31-step sequential algorithm.
// State lives in LDS; per-step global traffic is only the weight reads
// needed for the selected pair (W_tree GEMV) and the row refresh (W_a1).
__global__ __launch_bounds__(NT)
void hrl_kernel(const float* __restrict__ x_emb,    // 48*128
                const float* __restrict__ W_leaf,   // 128*256
                const float* __restrict__ b_leaf,   // 256
                const float* __restrict__ W_tree,   // 256*640
                const float* __restrict__ b_tree,   // 640
                const float* __restrict__ W_a1,     // 256*128
                const float* __restrict__ b_a1,     // 128
                const float* __restrict__ W_a2,     // 128
                const float* __restrict__ b_a2,     // 1
                const int*   __restrict__ bidx,     // 32
                float* __restrict__ out)            // 4096 + 1 + 1 + 62
{
    __shared__ float sh_hidden[BN][DN];   // 16 KB
    __shared__ float sh_cell[BN][DN];     // 16 KB
    __shared__ float sh_uT[DN][BN];       // 16 KB (transposed: conflict-free col reads)
    __shared__ float sh_vT[DN][BN];       // 16 KB
    __shared__ float sh_score[BN][BN];    // 4 KB
    __shared__ float sh_g[5*DN];          // 2.5 KB
    __shared__ float sh_w2[DN];
    __shared__ float sh_b1[DN];
    __shared__ float sh_mask[BN];
    __shared__ int   sh_bidx[BN];
    __shared__ float red_a[NT/64], red_b[NT/64];
    __shared__ int   red_i[NT/64];
    __shared__ float sh_maxv;
    __shared__ int   sh_head, sh_dep;
    __shared__ float sh_b2;

    const int tid  = threadIdx.x;
    const int lane = tid & 63;
    const int wid  = tid >> 6;

    if (tid < DN) { sh_w2[tid] = W_a2[tid]; sh_b1[tid] = b_a1[tid]; }
    if (tid < BN) { sh_mask[tid] = 1.0f; sh_bidx[tid] = bidx[tid]; }
    if (tid == 0) sh_b2 = b_a2[0];
    __syncthreads();

    // ---- leaf projections: hidden/cell = (x_emb[bidx] @ W_leaf + b_leaf) split
    for (int w = tid; w < BN * 2 * DN; w += NT) {
        const int i = w >> 8;          // row 0..31
        const int c = w & 255;         // col 0..255
        const float* xr = x_emb + sh_bidx[i] * DN;
        float acc = b_leaf[c];
        #pragma unroll 8
        for (int j = 0; j < DN; ++j) acc = fmaf(xr[j], W_leaf[j * 256 + c], acc);
        if (c < DN) sh_hidden[i][c] = acc; else sh_cell[i][c - DN] = acc;
    }
    __syncthreads();

    // ---- init u = hidden@A1_top, v = hidden@A1_bot (stored transposed)
    for (int w = tid; w < BN * 2 * DN; w += NT) {
        const int h = w >> 8;
        const int c = w & 255;
        const int k = c & 127;
        const float* Wp = W_a1 + (c >= DN ? DN * DN : 0) + k;
        float acc = 0.0f;
        #pragma unroll 8
        for (int j = 0; j < DN; ++j) acc = fmaf(sh_hidden[h][j], Wp[j * DN], acc);
        if (c < DN) sh_uT[k][h] = acc; else sh_vT[k][h] = acc;
    }
    __syncthreads();

    // ---- init full 32x32 score matrix: score[h,d] = w2 . relu(u[h]+v[d]+b1) + b2
    {
        const int h = tid >> 5, d = tid & 31;
        float acc = sh_b2;
        #pragma unroll 4
        for (int k = 0; k < DN; ++k) {
            const float pre = sh_uT[k][h] + sh_vT[k][d] + sh_b1[k];
            acc = fmaf(sh_w2[k], fmaxf(pre, 0.0f), acc);
        }
        sh_score[h][d] = acc;
    }
    __syncthreads();

    float lps_sum = 0.0f, ents_sum = 0.0f;   // live in thread 0 only

    for (int t = 0; t < NSTEP; ++t) {
        const int h = tid >> 5, d = tid & 31;
        const bool valid = (h != d) && (sh_mask[d] > 0.0f);
        const float s = valid ? sh_score[h][d] : -3.0e38f;

        // ---- reduce: max over valid scores
        float m = s;
        #pragma unroll
        for (int off = 32; off > 0; off >>= 1) m = fmaxf(m, __shfl_down(m, off));
        if (lane == 0) red_a[wid] = m;
        __syncthreads();
        if (tid == 0) {
            float mm = red_a[0];
            for (int i = 1; i < NT / 64; ++i) mm = fmaxf(mm, red_a[i]);
            sh_maxv = mm;
        }
        __syncthreads();
        const float maxv = sh_maxv;

        // ---- reduce: sum exp, sum x*exp, first index achieving max (tie -> min idx)
        float e = 0.0f, s1 = 0.0f;
        int cand = 0x7fffffff;
        if (valid) {
            const float x = s - maxv;
            const float ex = expf(x);
            e = ex; s1 = ex * x;
            if (s == maxv) cand = tid;
        }
        #pragma unroll
        for (int off = 32; off > 0; off >>= 1) {
            e    += __shfl_down(e, off);
            s1   += __shfl_down(s1, off);
            cand  = min(cand, __shfl_down(cand, off));
        }
        if (lane == 0) { red_a[wid] = e; red_b[wid] = s1; red_i[wid] = cand; }
        __syncthreads();
        if (tid == 0) {
            float E = 0.0f, S1 = 0.0f; int idx = 0x7fffffff;
            for (int i = 0; i < NT / 64; ++i) {
                E += red_a[i]; S1 += red_b[i]; idx = min(idx, red_i[i]);
            }
            const float logE = logf(E);
            const int hh = idx >> 5, dd = idx & 31;
            lps_sum += (sh_score[hh][dd] - maxv) - logE;          // logp[idx]
            const float nv = (float)((BN - t) * (BN - 1));        // n_valid
            ents_sum += -(S1 / E - logE) / logf(nv);              // entropy
            sh_head = hh; sh_dep = dd;
            sh_mask[dd] = 0.0f;
            out[BN * DN + 2 + 2 * t]     = (float)sh_bidx[hh];    // edges
            out[BN * DN + 2 + 2 * t + 1] = (float)sh_bidx[dd];
        }
        __syncthreads();
        const int head = sh_head, dep = sh_dep;

        // ---- gates GEMV for the selected pair only (the heavy phase: 640KB L2)
        if (tid < 5 * DN) {
            const int j = tid;
            const float* Wh = W_tree + j;               // rows 0..127, stride 640
            const float* Wd = W_tree + DN * 5 * DN + j; // rows 128..255
            float acc = b_tree[j];
            #pragma unroll 8
            for (int k = 0; k < DN; ++k) {
                acc = fmaf(sh_hidden[head][k], Wh[k * 640], acc);
                acc = fmaf(sh_hidden[dep][k],  Wd[k * 640], acc);
            }
            sh_g[j] = acc;
        }
        __syncthreads();

        // ---- c_new/h_new for selected pair; in-place row update
        if (tid < DN) {
            const int k = tid;
            const float ig = sigf(sh_g[k]);
            const float fl = sigf(sh_g[DN + k]);
            const float fr = sigf(sh_g[2 * DN + k]);
            const float gg = tanhf(sh_g[3 * DN + k]);
            const float og = sigf(sh_g[4 * DN + k]);
            const float c  = ig * gg + fl * sh_cell[head][k] + fr * sh_cell[dep][k];
            sh_cell[head][k]   = c;
            sh_hidden[head][k] = og * tanhf(c);
        }
        __syncthreads();

        // ---- refresh u[head,:], v[head,:]
        if (tid < 2 * DN) {
            const int k = tid & 127;
            const float* Wp = W_a1 + (tid >= DN ? DN * DN : 0) + k;
            float acc = 0.0f;
            #pragma unroll 8
            for (int j = 0; j < DN; ++j) acc = fmaf(sh_hidden[head][j], Wp[j * DN], acc);
            if (tid < DN) sh_uT[k][head] = acc; else sh_vT[k][head] = acc;
        }
        __syncthreads();

        // ---- refresh score row head and column head
        if (tid < 2 * BN) {
            const int hh = (tid < BN) ? head : (tid - BN);
            const int dd = (tid < BN) ? tid  : head;
            if (hh != dd) {
                float acc = sh_b2;
                #pragma unroll 4
                for (int k = 0; k < DN; ++k) {
                    const float pre = sh_uT[k][hh] + sh_vT[k][dd] + sh_b1[k];
                    acc = fmaf(sh_w2[k], fmaxf(pre, 0.0f), acc);
                }
                sh_score[hh][dd] = acc;
            }
        }
        __syncthreads();
    }

    // ---- outputs: hidden (4096), sum lps (1), mean ents (1); edges written in-loop
    for (int w = tid; w < BN * DN; w += NT) out[w] = sh_hidden[w >> 7][w & 127];
    if (tid == 0) {
        out[BN * DN]     = lps_sum;
        out[BN * DN + 1] = ents_sum / (float)NSTEP;
    }
}

extern "C" void kernel_launch(void* const* d_in, const int* in_sizes, int n_in,
                              void* d_out, int out_size, void* d_ws, size_t ws_size,
                              hipStream_t stream) {
    const float* x_emb  = (const float*)d_in[0];
    const float* W_leaf = (const float*)d_in[1];
    const float* b_leaf = (const float*)d_in[2];
    const float* W_tree = (const float*)d_in[3];
    const float* b_tree = (const float*)d_in[4];
    const float* W_a1   = (const float*)d_in[5];
    const float* b_a1   = (const float*)d_in[6];
    const float* W_a2   = (const float*)d_in[7];
    const float* b_a2   = (const float*)d_in[8];
    const int*   bidx   = (const int*)d_in[9];
    float* out = (float*)d_out;

    hipLaunchKernelGGL(hrl_kernel, dim3(1), dim3(NT), 0, stream,
                       x_emb, W_leaf, b_leaf, W_tree, b_tree,
                       W_a1, b_a1, W_a2, b_a2, bidx, out);
}